// Round 3
// baseline (280.769 us; speedup 1.0000x reference)
//
#include <hip/hip_runtime.h>

// DeepFM fused ranker, fp32.
// R3: block-wide GEMV for the MLP — wave w owns a neuron slice and processes
// ALL 32 rows of the block, so W1/W2 stream through L1 once per block (4x
// less than per-wave GEMV). Packed-fp32 math (v_pk_fma_f32) via
// ext_vector_type(2) halves VALU instruction count. Weights pre-packed
// lane-major in d_ws for fully coalesced loads.

typedef float v2f __attribute__((ext_vector_type(2)));

#define WAVES_PER_BLOCK 4
#define ROWS_PER_WAVE 8
#define ROWS_PER_BLOCK 32

// ---- pre-pass ----
// W1p[(w*50 + k4)*32 + j'] = float4{ W1[j][4k4 .. 4k4+3] }, j = 32w + j'
// W2p[(w*32 + k4)*16 + j'] = float4{ W2[j][4k4 .. 4k4+3] }, j = 16w + j'
__global__ void pack_weights(const float* __restrict__ W1, const float* __restrict__ W2,
                             float4* __restrict__ W1p, float4* __restrict__ W2p) {
    const int idx = blockIdx.x * blockDim.x + threadIdx.x;
    if (idx < 6400) {
        const int w = idx / 1600, rem = idx % 1600;
        const int k4 = rem >> 5, jp = rem & 31;
        const int j = w * 32 + jp;
        const float* r = W1 + j * 200 + 4 * k4;
        W1p[idx] = make_float4(r[0], r[1], r[2], r[3]);
    }
    if (idx < 2048) {
        const int w = idx / 512, rem = idx % 512;
        const int k4 = rem >> 4, jp = rem & 15;
        const int j = w * 16 + jp;
        const float* r = W2 + j * 128 + 4 * k4;
        W2p[idx] = make_float4(r[0], r[1], r[2], r[3]);
    }
}

__global__ __launch_bounds__(256) void deepfm_kernel(
    const int* __restrict__ user_id, const int* __restrict__ item_id,
    const int* __restrict__ gender_, const int* __restrict__ age_,
    const int* __restrict__ occ_, const int* __restrict__ genre_ids,
    const float* __restrict__ genre_mask, const float* __restrict__ dense,
    const float* __restrict__ fo_user, const float* __restrict__ fo_item,
    const float* __restrict__ fo_gender, const float* __restrict__ fo_age,
    const float* __restrict__ fo_occ, const float* __restrict__ fo_genre,
    const float* __restrict__ emb_user, const float* __restrict__ emb_item,
    const float* __restrict__ emb_gender, const float* __restrict__ emb_age,
    const float* __restrict__ emb_occ, const float* __restrict__ emb_genre,
    const float* __restrict__ dense_W, const float* __restrict__ dense_b,
    const float4* __restrict__ W1p, const float* __restrict__ b1,
    const float4* __restrict__ W2p, const float* __restrict__ b2,
    const float* __restrict__ Wout, const float* __restrict__ bout,
    float* __restrict__ out, int B)
{
    __shared__ float lds_di[ROWS_PER_BLOCK][200];   // deep_in; h1[32][128] overlays later
    __shared__ float lds_rs[ROWS_PER_BLOCK];        // first+second per row
    __shared__ float lds_part[ROWS_PER_BLOCK][WAVES_PER_BLOCK];  // Wout partials

    const int tid = threadIdx.x;
    const int wid = tid >> 6;
    const int lane = tid & 63;
    const int blockRow0 = blockIdx.x * ROWS_PER_BLOCK;

    // ---------------- Phase A: gather + FM first/second order (wave owns 8 rows) ----
    {
        const int rowBase = blockRow0 + wid * ROWS_PER_WAVE;
        int uid[ROWS_PER_WAVE], iid[ROWS_PER_WAVE], gg[ROWS_PER_WAVE],
            aa[ROWS_PER_WAVE], oo[ROWS_PER_WAVE];
        #pragma unroll
        for (int r = 0; r < ROWS_PER_WAVE; ++r) {
            int row = rowBase + r; if (row >= B) row = B - 1;
            uid[r] = user_id[row]; iid[r] = item_id[row];
            gg[r] = gender_[row];  aa[r] = age_[row];  oo[r] = occ_[row];
        }

        #pragma unroll
        for (int r = 0; r < ROWS_PER_WAVE; ++r) {
            int row = rowBase + r; if (row >= B) row = B - 1;
            const int ri = wid * ROWS_PER_WAVE + r;     // row within block

            int gid[6]; float mk[6]; float msum = 0.f;
            #pragma unroll
            for (int t = 0; t < 6; ++t) {
                gid[t] = genre_ids[row * 6 + t];
                mk[t]  = genre_mask[row * 6 + t];
                msum  += mk[t];
            }
            const float inv_den = 1.0f / fmaxf(msum, 1.0f);

            float pe_sum = 0.f, pe_sq = 0.f;
            {
                float v = (lane < 32) ? emb_user[(size_t)uid[r] * 32 + lane]
                                      : emb_item[(size_t)iid[r] * 32 + (lane - 32)];
                lds_di[ri][lane] = v;
                pe_sum += v; pe_sq += v * v;
            }
            {
                float v = (lane < 32) ? emb_gender[gg[r] * 32 + lane]
                                      : emb_age[aa[r] * 32 + (lane - 32)];
                lds_di[ri][64 + lane] = v;
                pe_sum += v; pe_sq += v * v;
            }
            {
                float v;
                if (lane < 32) {
                    v = emb_occ[oo[r] * 32 + lane];
                } else {
                    const int d = lane - 32;
                    float s = 0.f;
                    #pragma unroll
                    for (int t = 0; t < 6; ++t) s += mk[t] * emb_genre[gid[t] * 32 + d];
                    v = s * inv_den;
                }
                lds_di[ri][128 + lane] = v;
                pe_sum += v; pe_sq += v * v;
            }
            if (lane < 8) lds_di[ri][192 + lane] = dense[(size_t)row * 8 + lane];

            float s2 = pe_sum + __shfl_xor(pe_sum, 32);
            float ss = pe_sq  + __shfl_xor(pe_sq, 32);
            float t2 = 0.5f * (s2 * s2 - ss);
            #pragma unroll
            for (int off = 16; off >= 1; off >>= 1) t2 += __shfl_xor(t2, off);

            float fo = fo_user[uid[r]] + fo_item[iid[r]] + fo_gender[gg[r]]
                     + fo_age[aa[r]] + fo_occ[oo[r]];
            float fg = 0.f;
            #pragma unroll
            for (int t = 0; t < 6; ++t) fg += mk[t] * fo_genre[gid[t]];
            fo += fg * inv_den;
            float dd = 0.f;
            #pragma unroll
            for (int j = 0; j < 8; ++j) dd += dense[(size_t)row * 8 + j] * dense_W[j];
            fo += dd + dense_b[0];

            if (lane == 0) lds_rs[ri] = fo + t2;
        }
    }
    __syncthreads();

    // ---------------- Phase B: h1 = relu(deep_in @ W1^T + b1), block-wide ----------
    // wave wid owns neurons [32*wid, 32*wid+32); lane: neuron j'=lane&31,
    // row half = lane>>5 (rows half*16 .. half*16+16).
    const int jp1 = lane & 31;
    const int half = lane >> 5;

    v2f acc[16];
    #pragma unroll
    for (int rp = 0; rp < 16; ++rp) acc[rp] = (v2f)(0.f);

    {
        const float4* __restrict__ W1b = W1p + wid * 1600;           // 50*32 float4 slice
        const float4* __restrict__ dv = reinterpret_cast<const float4*>(&lds_di[0][0]); // [32][50]

        for (int k4 = 0; k4 < 50; ++k4) {
            const float4 w = W1b[k4 * 32 + jp1];                     // coalesced 512B
            const v2f w01 = { w.x, w.y }, w23 = { w.z, w.w };
            #pragma unroll
            for (int rp = 0; rp < 16; ++rp) {
                const float4 a = dv[(half * 16 + rp) * 50 + k4];     // 2 uniform addrs
                const v2f a01 = { a.x, a.y }, a23 = { a.z, a.w };
                acc[rp] = __builtin_elementwise_fma(w01, a01, acc[rp]);
                acc[rp] = __builtin_elementwise_fma(w23, a23, acc[rp]);
            }
        }
    }
    __syncthreads();   // all deep_in reads complete; safe to overlay h1

    float* __restrict__ h1b = &lds_di[0][0];       // h1[r][j] at r*128 + j (16 KB)
    {
        const float bb = b1[wid * 32 + jp1];
        #pragma unroll
        for (int rp = 0; rp < 16; ++rp) {
            const float h = fmaxf(acc[rp].x + acc[rp].y + bb, 0.f);
            h1b[(half * 16 + rp) * 128 + wid * 32 + jp1] = h;
        }
    }
    __syncthreads();

    // ---------------- Phase C: h2 = relu(h1 @ W2^T + b2), block-wide ---------------
    // wave wid owns neurons [16*wid, 16*wid+16); lane: j'=lane&15, row group rg=lane>>4
    const int jp2 = lane & 15;
    const int rg = lane >> 4;

    v2f acc2[8];
    #pragma unroll
    for (int ri = 0; ri < 8; ++ri) acc2[ri] = (v2f)(0.f);

    {
        const float4* __restrict__ W2b = W2p + wid * 512;            // 32*16 float4 slice
        const float4* __restrict__ h1v = reinterpret_cast<const float4*>(h1b); // [32][32]

        for (int k4 = 0; k4 < 32; ++k4) {
            const float4 w = W2b[k4 * 16 + jp2];                     // coalesced 256B
            const v2f w01 = { w.x, w.y }, w23 = { w.z, w.w };
            #pragma unroll
            for (int ri = 0; ri < 8; ++ri) {
                const float4 h = h1v[(rg * 8 + ri) * 32 + k4];       // 4 uniform addrs
                const v2f h01 = { h.x, h.y }, h23 = { h.z, h.w };
                acc2[ri] = __builtin_elementwise_fma(w01, h01, acc2[ri]);
                acc2[ri] = __builtin_elementwise_fma(w23, h23, acc2[ri]);
            }
        }
    }

    // ---------------- Phase D: Wout dot + combine --------------------------------
    {
        const float bb2 = b2[wid * 16 + jp2];
        const float wo  = Wout[wid * 16 + jp2];
        #pragma unroll
        for (int ri = 0; ri < 8; ++ri) {
            const float h2 = fmaxf(acc2[ri].x + acc2[ri].y + bb2, 0.f);
            float v = wo * h2;
            // reduce over the 16-lane neuron group
            v += __shfl_xor(v, 1); v += __shfl_xor(v, 2);
            v += __shfl_xor(v, 4); v += __shfl_xor(v, 8);
            if (jp2 == 0) lds_part[rg * 8 + ri][wid] = v;
        }
    }
    __syncthreads();

    if (tid < ROWS_PER_BLOCK) {
        const int row = blockRow0 + tid;
        if (row < B) {
            const float deep = lds_part[tid][0] + lds_part[tid][1]
                             + lds_part[tid][2] + lds_part[tid][3] + bout[0];
            out[row] = deep + lds_rs[tid];
        }
    }
}

extern "C" void kernel_launch(void* const* d_in, const int* in_sizes, int n_in,
                              void* d_out, int out_size, void* d_ws, size_t ws_size,
                              hipStream_t stream) {
    const int B = in_sizes[0];

    float4* W1p = reinterpret_cast<float4*>(d_ws);                  // 6400 float4 = 100 KB
    float4* W2p = reinterpret_cast<float4*>((char*)d_ws + 102400);  // 2048 float4 = 32 KB

    pack_weights<<<25, 256, 0, stream>>>(
        (const float*)d_in[22], (const float*)d_in[24], W1p, W2p);

    const int grid = (B + ROWS_PER_BLOCK - 1) / ROWS_PER_BLOCK;  // 512 at B=16384
    deepfm_kernel<<<grid, 256, 0, stream>>>(
        (const int*)d_in[0],  (const int*)d_in[1],  (const int*)d_in[2],
        (const int*)d_in[3],  (const int*)d_in[4],  (const int*)d_in[5],
        (const float*)d_in[6],  (const float*)d_in[7],
        (const float*)d_in[8],  (const float*)d_in[9],  (const float*)d_in[10],
        (const float*)d_in[11], (const float*)d_in[12], (const float*)d_in[13],
        (const float*)d_in[14], (const float*)d_in[15], (const float*)d_in[16],
        (const float*)d_in[17], (const float*)d_in[18], (const float*)d_in[19],
        (const float*)d_in[20], (const float*)d_in[21],
        W1p, (const float*)d_in[23],
        W2p, (const float*)d_in[25],
        (const float*)d_in[26], (const float*)d_in[27],
        (float*)d_out, B);
}

// Round 4
// 261.975 us; speedup vs baseline: 1.0717x; 1.0717x over previous
//
#include <hip/hip_runtime.h>

// DeepFM fused ranker, fp32.
// R4: minimize instruction issue in the MLP GEMVs.
//  - Block-wide Phase B: wave owns a 32-neuron slice (W1 streamed once per
//    block from L2); lane tile = 2 neurons x 8 rows -> per k4: 2 coalesced
//    weight b128 + 8 broadcast act b128 + 16 v_pk_fma_f32.
//  - Weights pre-packed pair-transposed so pk-fma needs no lane shuffling.
//  - LDS deep_in row stride 204 (+ rows rh+4r per lane) and h1 stride 132:
//    all act b128 reads bank-conflict-free by construction.

typedef float v2f __attribute__((ext_vector_type(2)));
static __device__ __forceinline__ v2f bc2(float x) { v2f r; r.x = x; r.y = x; return r; }

#define ROWS_PER_BLOCK 32
#define ROWS_PER_WAVE 8
#define DI_STRIDE 204            // floats; 51 float4
#define H1_STRIDE 132            // floats; 33 float4

// ---- pre-pass: pair-transposed packed weights ----
// W1p[((wid*50+k4)*16+jp)*2+s] = {W1[j0][c],W1[j1][c],W1[j0][c+1],W1[j1][c+1]}
//   j0 = 32*wid + 2*jp, c = 4*k4 + 2*s
// W2p[((wid*32+k4)*8+jp)*2+s]  = same with j0 = 16*wid + 2*jp, row len 128
__global__ void pack_weights(const float* __restrict__ W1, const float* __restrict__ W2,
                             float4* __restrict__ W1p, float4* __restrict__ W2p) {
    const int idx = blockIdx.x * blockDim.x + threadIdx.x;
    if (idx < 6400) {
        const int s = idx & 1, jp = (idx >> 1) & 15, k4 = (idx >> 5) % 50, w = idx / 1600;
        const int j0 = w * 32 + 2 * jp, c = 4 * k4 + 2 * s;
        W1p[idx] = make_float4(W1[j0 * 200 + c],     W1[(j0 + 1) * 200 + c],
                               W1[j0 * 200 + c + 1], W1[(j0 + 1) * 200 + c + 1]);
    }
    if (idx < 2048) {
        const int s = idx & 1, jp = (idx >> 1) & 7, k4 = (idx >> 4) & 31, w = idx >> 9;
        const int j0 = w * 16 + 2 * jp, c = 4 * k4 + 2 * s;
        W2p[idx] = make_float4(W2[j0 * 128 + c],     W2[(j0 + 1) * 128 + c],
                               W2[j0 * 128 + c + 1], W2[(j0 + 1) * 128 + c + 1]);
    }
}

__global__ __launch_bounds__(256) void deepfm_kernel(
    const int* __restrict__ user_id, const int* __restrict__ item_id,
    const int* __restrict__ gender_, const int* __restrict__ age_,
    const int* __restrict__ occ_, const int* __restrict__ genre_ids,
    const float* __restrict__ genre_mask, const float* __restrict__ dense,
    const float* __restrict__ fo_user, const float* __restrict__ fo_item,
    const float* __restrict__ fo_gender, const float* __restrict__ fo_age,
    const float* __restrict__ fo_occ, const float* __restrict__ fo_genre,
    const float* __restrict__ emb_user, const float* __restrict__ emb_item,
    const float* __restrict__ emb_gender, const float* __restrict__ emb_age,
    const float* __restrict__ emb_occ, const float* __restrict__ emb_genre,
    const float* __restrict__ dense_W, const float* __restrict__ dense_b,
    const float4* __restrict__ W1p, const float* __restrict__ b1,
    const float4* __restrict__ W2p, const float* __restrict__ b2,
    const float* __restrict__ Wout, const float* __restrict__ bout,
    float* __restrict__ out, int B)
{
    __shared__ float lds_di[ROWS_PER_BLOCK][DI_STRIDE];   // 26.1 KB; h1[32][132] overlays
    __shared__ float lds_rs[ROWS_PER_BLOCK];
    __shared__ float lds_part[ROWS_PER_BLOCK][4];

    const int tid = threadIdx.x;
    const int wid = tid >> 6;
    const int lane = tid & 63;
    const int blockRow0 = blockIdx.x * ROWS_PER_BLOCK;

    // ---------------- Phase A: gather + FM first/second order (wave owns 8 rows) ----
    {
        const int rowBase = blockRow0 + wid * ROWS_PER_WAVE;
        int uid[ROWS_PER_WAVE], iid[ROWS_PER_WAVE], gg[ROWS_PER_WAVE],
            aa[ROWS_PER_WAVE], oo[ROWS_PER_WAVE];
        #pragma unroll
        for (int r = 0; r < ROWS_PER_WAVE; ++r) {
            int row = rowBase + r; if (row >= B) row = B - 1;
            uid[r] = user_id[row]; iid[r] = item_id[row];
            gg[r] = gender_[row];  aa[r] = age_[row];  oo[r] = occ_[row];
        }

        #pragma unroll
        for (int r = 0; r < ROWS_PER_WAVE; ++r) {
            int row = rowBase + r; if (row >= B) row = B - 1;
            const int ri = wid * ROWS_PER_WAVE + r;

            int gid[6]; float mk[6]; float msum = 0.f;
            #pragma unroll
            for (int t = 0; t < 6; ++t) {
                gid[t] = genre_ids[row * 6 + t];
                mk[t]  = genre_mask[row * 6 + t];
                msum  += mk[t];
            }
            const float inv_den = 1.0f / fmaxf(msum, 1.0f);

            float pe_sum = 0.f, pe_sq = 0.f;
            {
                float v = (lane < 32) ? emb_user[(size_t)uid[r] * 32 + lane]
                                      : emb_item[(size_t)iid[r] * 32 + (lane - 32)];
                lds_di[ri][lane] = v;
                pe_sum += v; pe_sq += v * v;
            }
            {
                float v = (lane < 32) ? emb_gender[gg[r] * 32 + lane]
                                      : emb_age[aa[r] * 32 + (lane - 32)];
                lds_di[ri][64 + lane] = v;
                pe_sum += v; pe_sq += v * v;
            }
            {
                float v;
                if (lane < 32) {
                    v = emb_occ[oo[r] * 32 + lane];
                } else {
                    const int d = lane - 32;
                    float s = 0.f;
                    #pragma unroll
                    for (int t = 0; t < 6; ++t) s += mk[t] * emb_genre[gid[t] * 32 + d];
                    v = s * inv_den;
                }
                lds_di[ri][128 + lane] = v;
                pe_sum += v; pe_sq += v * v;
            }
            if (lane < 8) lds_di[ri][192 + lane] = dense[(size_t)row * 8 + lane];

            float s2 = pe_sum + __shfl_xor(pe_sum, 32);
            float ss = pe_sq  + __shfl_xor(pe_sq, 32);
            float t2 = 0.5f * (s2 * s2 - ss);
            #pragma unroll
            for (int off = 16; off >= 1; off >>= 1) t2 += __shfl_xor(t2, off);

            float fo = fo_user[uid[r]] + fo_item[iid[r]] + fo_gender[gg[r]]
                     + fo_age[aa[r]] + fo_occ[oo[r]];
            float fg = 0.f;
            #pragma unroll
            for (int t = 0; t < 6; ++t) fg += mk[t] * fo_genre[gid[t]];
            fo += fg * inv_den;
            float dd = 0.f;
            #pragma unroll
            for (int j = 0; j < 8; ++j) dd += dense[(size_t)row * 8 + j] * dense_W[j];
            fo += dd + dense_b[0];

            if (lane == 0) lds_rs[ri] = fo + t2;
        }
    }
    __syncthreads();

    // ---------------- Phase B: h1 = relu(deep_in @ W1^T + b1) ----------------------
    // wave owns neurons [32*wid, 32*wid+32); lane: jp=lane&15 -> pair {2jp,2jp+1},
    // rh=lane>>4 -> rows {rh+4r}. Bank-conflict-free by stride-204 + rh+4r.
    const int jp1 = lane & 15;
    const int rh  = lane >> 4;

    v2f acc[ROWS_PER_WAVE];
    #pragma unroll
    for (int r = 0; r < ROWS_PER_WAVE; ++r) acc[r] = bc2(0.f);

    {
        const float4* __restrict__ W1b = W1p + wid * 1600;
        const float4* __restrict__ dv = reinterpret_cast<const float4*>(&lds_di[0][0]); // stride 51

        for (int k4 = 0; k4 < 50; ++k4) {
            const float4 wa = W1b[(k4 * 16 + jp1) * 2 + 0];   // {j0k0,j1k0,j0k1,j1k1}
            const float4 wb = W1b[(k4 * 16 + jp1) * 2 + 1];   // {j0k2,j1k2,j0k3,j1k3}
            const v2f w0 = { wa.x, wa.y }, w1 = { wa.z, wa.w };
            const v2f w2 = { wb.x, wb.y }, w3 = { wb.z, wb.w };
            #pragma unroll
            for (int r = 0; r < ROWS_PER_WAVE; ++r) {
                const float4 a = dv[(rh + 4 * r) * 51 + k4];
                acc[r] = __builtin_elementwise_fma(w0, bc2(a.x), acc[r]);
                acc[r] = __builtin_elementwise_fma(w1, bc2(a.y), acc[r]);
                acc[r] = __builtin_elementwise_fma(w2, bc2(a.z), acc[r]);
                acc[r] = __builtin_elementwise_fma(w3, bc2(a.w), acc[r]);
            }
        }
    }
    __syncthreads();   // all deep_in reads done; overlay h1

    float* __restrict__ h1b = &lds_di[0][0];   // h1[row][j] at row*132 + j
    {
        const int j0 = wid * 32 + 2 * jp1;
        const float2 bb = *reinterpret_cast<const float2*>(b1 + j0);
        #pragma unroll
        for (int r = 0; r < ROWS_PER_WAVE; ++r) {
            const int row = rh + 4 * r;
            reinterpret_cast<float2*>(h1b)[(row * H1_STRIDE + j0) >> 1] =
                make_float2(fmaxf(acc[r].x + bb.x, 0.f), fmaxf(acc[r].y + bb.y, 0.f));
        }
    }
    __syncthreads();

    // ---------------- Phase C: h2 = relu(h1 @ W2^T + b2) ---------------------------
    // wave owns neurons [16*wid,16*wid+16); lane: jp2=lane&7 -> pair, rh2=lane>>3 ->
    // rows {rh2+8t}. Conflict-free via stride 132.
    const int jp2 = lane & 7;
    const int rh2 = lane >> 3;

    v2f acc2[4];
    #pragma unroll
    for (int t = 0; t < 4; ++t) acc2[t] = bc2(0.f);

    {
        const float4* __restrict__ W2b = W2p + wid * 512;
        const float4* __restrict__ h1v = reinterpret_cast<const float4*>(h1b); // stride 33

        for (int k4 = 0; k4 < 32; ++k4) {
            const float4 wa = W2b[(k4 * 8 + jp2) * 2 + 0];
            const float4 wb = W2b[(k4 * 8 + jp2) * 2 + 1];
            const v2f w0 = { wa.x, wa.y }, w1 = { wa.z, wa.w };
            const v2f w2 = { wb.x, wb.y }, w3 = { wb.z, wb.w };
            #pragma unroll
            for (int t = 0; t < 4; ++t) {
                const float4 h = h1v[(rh2 + 8 * t) * 33 + k4];
                acc2[t] = __builtin_elementwise_fma(w0, bc2(h.x), acc2[t]);
                acc2[t] = __builtin_elementwise_fma(w1, bc2(h.y), acc2[t]);
                acc2[t] = __builtin_elementwise_fma(w2, bc2(h.z), acc2[t]);
                acc2[t] = __builtin_elementwise_fma(w3, bc2(h.w), acc2[t]);
            }
        }
    }

    // ---------------- Phase D: Wout dot + combine ----------------------------------
    {
        const int j0 = wid * 16 + 2 * jp2;
        const float2 bb2 = *reinterpret_cast<const float2*>(b2 + j0);
        const float2 wo  = *reinterpret_cast<const float2*>(Wout + j0);
        #pragma unroll
        for (int t = 0; t < 4; ++t) {
            const float h2x = fmaxf(acc2[t].x + bb2.x, 0.f);
            const float h2y = fmaxf(acc2[t].y + bb2.y, 0.f);
            float v = wo.x * h2x + wo.y * h2y;
            v += __shfl_xor(v, 1); v += __shfl_xor(v, 2); v += __shfl_xor(v, 4);
            if (jp2 == 0) lds_part[rh2 + 8 * t][wid] = v;
        }
    }
    __syncthreads();

    if (tid < ROWS_PER_BLOCK) {
        const int row = blockRow0 + tid;
        if (row < B) {
            const float deep = lds_part[tid][0] + lds_part[tid][1]
                             + lds_part[tid][2] + lds_part[tid][3] + bout[0];
            out[row] = deep + lds_rs[tid];
        }
    }
}

extern "C" void kernel_launch(void* const* d_in, const int* in_sizes, int n_in,
                              void* d_out, int out_size, void* d_ws, size_t ws_size,
                              hipStream_t stream) {
    const int B = in_sizes[0];

    float4* W1p = reinterpret_cast<float4*>(d_ws);                  // 6400 float4 = 100 KB
    float4* W2p = reinterpret_cast<float4*>((char*)d_ws + 102400);  // 2048 float4 = 32 KB

    pack_weights<<<25, 256, 0, stream>>>(
        (const float*)d_in[22], (const float*)d_in[24], W1p, W2p);

    const int grid = (B + ROWS_PER_BLOCK - 1) / ROWS_PER_BLOCK;  // 512 at B=16384
    deepfm_kernel<<<grid, 256, 0, stream>>>(
        (const int*)d_in[0],  (const int*)d_in[1],  (const int*)d_in[2],
        (const int*)d_in[3],  (const int*)d_in[4],  (const int*)d_in[5],
        (const float*)d_in[6],  (const float*)d_in[7],
        (const float*)d_in[8],  (const float*)d_in[9],  (const float*)d_in[10],
        (const float*)d_in[11], (const float*)d_in[12], (const float*)d_in[13],
        (const float*)d_in[14], (const float*)d_in[15], (const float*)d_in[16],
        (const float*)d_in[17], (const float*)d_in[18], (const float*)d_in[19],
        (const float*)d_in[20], (const float*)d_in[21],
        W1p, (const float*)d_in[23],
        W2p, (const float*)d_in[25],
        (const float*)d_in[26], (const float*)d_in[27],
        (float*)d_out, B);
}